// Round 7
// baseline (223.216 us; speedup 1.0000x reference)
//
#include <hip/hip_runtime.h>
#include <math.h>

// Problem constants
#define Bn   8
#define Cc   256     // input channels
#define Cin  128     // inter channels
#define Hh   64
#define Ww   64
#define Nn   4096    // H*W
#define Npl  1024    // pooled pixels (32*32)
#define EPSf 1e-5f

typedef __attribute__((ext_vector_type(8))) short    short8;   // 8 bf16
typedef __attribute__((ext_vector_type(8))) _Float16 half8;    // 8 fp16
typedef __attribute__((ext_vector_type(4))) float    floatx4;  // MFMA C/D

__device__ __forceinline__ unsigned short f2bf(float f) {
    unsigned int u = __float_as_uint(f);
    u += 0x7fffu + ((u >> 16) & 1u);
    return (unsigned short)(u >> 16);
}
__device__ __forceinline__ unsigned short f2h(float f) {
    _Float16 h = (_Float16)f;
    return __builtin_bit_cast(unsigned short, h);
}
__device__ __forceinline__ float h2f(unsigned short u) {
    return (float)__builtin_bit_cast(_Float16, u);
}

// ---------------------------------------------------------------------------
// Kernel 0 (prep): fp16 weight variants.
//  - g: fp16 hi. theta/phi: fp16 hi + fp16 lo (hi+lo ~ 22-bit mantissa).
//  - Wh = fp16(W_w * gamma/sqrt(var+eps)); cvec = (W_b-mean)*inv + beta.
// ---------------------------------------------------------------------------
__global__ __launch_bounds__(256) void k_prep(
    const float* __restrict__ g_w, const float* __restrict__ th_w,
    const float* __restrict__ ph_w,
    const float* __restrict__ W_w, const float* __restrict__ W_b,
    const float* __restrict__ gamma, const float* __restrict__ beta,
    const float* __restrict__ mean,  const float* __restrict__ var,
    unsigned short* __restrict__ gWh,
    unsigned short* __restrict__ thWh, unsigned short* __restrict__ thWl,
    unsigned short* __restrict__ phWh, unsigned short* __restrict__ phWl,
    unsigned short* __restrict__ Wh, float* __restrict__ cvec)
{
    int i = blockIdx.x * 256 + threadIdx.x;
    if (i < 98304) {                          // 3 x 128 x 256 conv weights
        int seg = i >> 15;                    // 0:g 1:theta 2:phi
        int idx = i & 32767;
        float v = (seg == 0 ? g_w : (seg == 1 ? th_w : ph_w))[idx];
        unsigned short hi = f2h(v);
        if (seg == 0) gWh[idx] = hi;
        else {
            (seg == 1 ? thWh : phWh)[idx] = hi;
            (seg == 1 ? thWl : phWl)[idx] = f2h(v - h2f(hi));
        }
    } else {
        int j = i - 98304;                    // 0..32767 : W fold (256x128)
        int o = j >> 7;
        float inv = gamma[o] * rsqrtf(var[o] + EPSf);
        Wh[j] = f2h(W_w[j] * inv);
        if (j < Cc) {
            float invi = gamma[j] * rsqrtf(var[j] + EPSf);
            cvec[j] = (W_b[j] - mean[j]) * invi + beta[j];
        }
    }
}

// ---------------------------------------------------------------------------
// Kernel 1: fused conv1x1 g/theta/phi via fp16 MFMA, split-precision on
// theta/phi (hi*hi + hi*lo + lo*hi). Outputs:
//   thetaT: [B,4096,128] fp16   phiPt: [B,1024,128] fp16   gPc: [B,128,1024] bf16
// ---------------------------------------------------------------------------
#define XPAD 264

__global__ __launch_bounds__(256, 2) void k_conv3(
    const float* __restrict__ x,
    const unsigned short* __restrict__ gWh,
    const unsigned short* __restrict__ thWh, const unsigned short* __restrict__ thWl,
    const unsigned short* __restrict__ phWh, const unsigned short* __restrict__ phWl,
    const float* __restrict__ g_b, const float* __restrict__ th_b,
    const float* __restrict__ ph_b,
    unsigned short* __restrict__ thetaT,
    unsigned short* __restrict__ gPc,
    unsigned short* __restrict__ phiPt)
{
    __shared__ __align__(16) unsigned short Xhi[64 * XPAD];   // 33 KB
    __shared__ __align__(16) unsigned short Xlo[64 * XPAD];   // 33 KB

    const int t    = threadIdx.x;
    const int w    = t >> 6;
    const int l    = t & 63;
    const int quad = l >> 4;
    const int l16  = l & 15;
    const int b    = blockIdx.x >> 6;
    const int tile = blockIdx.x & 63;
    const int ty   = tile >> 1;
    const int tx   = tile & 1;

    {
        const float4* xg = (const float4*)x;
        unsigned int* XhiW = (unsigned int*)Xhi;
        unsigned int* XloW = (unsigned int*)Xlo;
        #pragma unroll
        for (int it = 0; it < 8; ++it) {
            int idx = t + 256 * it;          // 0..2047
            int c2  = idx >> 4;
            int p4  = idx & 15;
            int n   = (2 * ty + (p4 >> 3)) * Ww + tx * 32 + (p4 & 7) * 4;
            float4 va = xg[((size_t)(b * Cc + 2 * c2) * Nn + n) >> 2];
            float4 vb = xg[((size_t)(b * Cc + 2 * c2 + 1) * Nn + n) >> 2];
            const float fa[4] = {va.x, va.y, va.z, va.w};
            const float fb[4] = {vb.x, vb.y, vb.z, vb.w};
            #pragma unroll
            for (int i = 0; i < 4; ++i) {
                int px = p4 * 4 + i;
                unsigned short ha = f2h(fa[i]), hb = f2h(fb[i]);
                unsigned short la = f2h(fa[i] - h2f(ha));
                unsigned short lb = f2h(fb[i] - h2f(hb));
                XhiW[px * 132 + c2] = (unsigned int)ha | ((unsigned int)hb << 16);
                XloW[px * 132 + c2] = (unsigned int)la | ((unsigned int)lb << 16);
            }
        }
    }
    __syncthreads();

    floatx4 acc[6][4] = {};

    #pragma unroll 2
    for (int kd = 0; kd < 8; ++kd) {
        half8 bhi[4], blo[4];
        #pragma unroll
        for (int nt = 0; nt < 4; ++nt) {
            bhi[nt] = *(const half8*)&Xhi[(nt * 16 + l16) * XPAD + kd * 32 + quad * 8];
            blo[nt] = *(const half8*)&Xlo[(nt * 16 + l16) * XPAD + kd * 32 + quad * 8];
        }
        #pragma unroll
        for (int ti = 0; ti < 6; ++ti) {
            int ot  = w + 4 * ti;
            int seg = ot >> 3;
            size_t aoff = (size_t)((ot & 7) * 16 + l16) * Cc + kd * 32 + quad * 8;
            const unsigned short* wh = (seg == 0 ? gWh : (seg == 1 ? thWh : phWh));
            half8 ah = *(const half8*)&wh[aoff];
            #pragma unroll
            for (int nt = 0; nt < 4; ++nt)
                acc[ti][nt] = __builtin_amdgcn_mfma_f32_16x16x32_f16(ah, bhi[nt], acc[ti][nt], 0, 0, 0);
            if (seg != 0) {
                const unsigned short* wl = (seg == 1 ? thWl : phWl);
                half8 al = *(const half8*)&wl[aoff];
                #pragma unroll
                for (int nt = 0; nt < 4; ++nt) {
                    acc[ti][nt] = __builtin_amdgcn_mfma_f32_16x16x32_f16(ah, blo[nt], acc[ti][nt], 0, 0, 0);
                    acc[ti][nt] = __builtin_amdgcn_mfma_f32_16x16x32_f16(al, bhi[nt], acc[ti][nt], 0, 0, 0);
                }
            }
        }
    }

    // epilogue: D[row=quad*4+r][col=l16]
    #pragma unroll
    for (int ti = 0; ti < 6; ++ti) {
        int ot  = w + 4 * ti;
        int seg = ot >> 3;
        int ol  = (ot & 7) * 16 + quad * 4;
        if (seg == 1) {                            // theta -> fp16 [n][o]
            float b0 = th_b[ol], b1 = th_b[ol + 1], b2 = th_b[ol + 2], b3 = th_b[ol + 3];
            #pragma unroll
            for (int nt = 0; nt < 4; ++nt) {
                int n = (2 * ty + (nt >> 1)) * Ww + tx * 32 + (nt & 1) * 16 + l16;
                ushort4 v;
                v.x = f2h(acc[ti][nt][0] + b0);
                v.y = f2h(acc[ti][nt][1] + b1);
                v.z = f2h(acc[ti][nt][2] + b2);
                v.w = f2h(acc[ti][nt][3] + b3);
                *(ushort4*)&thetaT[((size_t)b * Nn + n) * Cin + ol] = v;
            }
        } else {                                   // g / phi: 2x2 maxpool
            const float* bb = (seg == 0 ? g_b : ph_b);
            float b0 = bb[ol], b1 = bb[ol + 1], b2 = bb[ol + 2], b3 = bb[ol + 3];
            #pragma unroll
            for (int pp = 0; pp < 2; ++pp) {
                float pm[4];
                #pragma unroll
                for (int r = 0; r < 4; ++r) {
                    float m = fmaxf(acc[ti][pp][r], acc[ti][pp + 2][r]);
                    pm[r] = fmaxf(m, __shfl_xor(m, 1, 64));
                }
                int np = ty * 32 + tx * 16 + pp * 8 + (l16 >> 1);
                if ((l16 & 1) == 0) {
                    if (seg == 0) {                // g -> bf16 [o][np] (V dtype)
                        gPc[((size_t)b * Cin + ol + 0) * Npl + np] = f2bf(pm[0] + b0);
                        gPc[((size_t)b * Cin + ol + 1) * Npl + np] = f2bf(pm[1] + b1);
                        gPc[((size_t)b * Cin + ol + 2) * Npl + np] = f2bf(pm[2] + b2);
                        gPc[((size_t)b * Cin + ol + 3) * Npl + np] = f2bf(pm[3] + b3);
                    } else {                       // phi -> fp16 [np][o]
                        ushort4 v;
                        v.x = f2h(pm[0] + b0); v.y = f2h(pm[1] + b1);
                        v.z = f2h(pm[2] + b2); v.w = f2h(pm[3] + b3);
                        *(ushort4*)&phiPt[((size_t)b * Npl + np) * Cin + ol] = v;
                    }
                }
            }
        }
    }
}

// ---------------------------------------------------------------------------
// Kernel 2: flash attention, split-K (2 halves of 512 keys), fp16 QK^T MFMA,
// bf16 PV MFMA, fixed-shift softmax (exactly additive partials).
//   Q = thetaT fp16 [B,N,128], K = phiPt fp16 [B,Np,128], V^T = gPc bf16
//   Ypart fp32 [2][B,N,128] (unnormalized), Lpart fp32 [2][B,N]
// grid 1024 blocks -> 4 blocks/CU; LDS 26 KB (V direct from L2).
// ---------------------------------------------------------------------------
#define DPAD 136
#define PPAD 68
#define SSHIFT 20.0f

__global__ __launch_bounds__(256, 4) void k_attn(
    const unsigned short* __restrict__ thetaT,
    const unsigned short* __restrict__ phiPt,
    const unsigned short* __restrict__ gPc,
    float* __restrict__ Ypart, float* __restrict__ Lpart)
{
    __shared__ __align__(16) unsigned short Ks[64 * DPAD];     // 17.4 KB
    __shared__ __align__(16) unsigned short Ps[4][16 * PPAD];  // 8.7 KB

    const int t    = threadIdx.x;
    const int w    = t >> 6;
    const int l    = t & 63;
    const int quad = l >> 4;
    const int l16  = l & 15;
    const int b    = blockIdx.x >> 7;
    const int kh   = (blockIdx.x >> 6) & 1;   // K half
    const int qb   = blockIdx.x & 63;
    const int n0   = qb * 64;

    // Q A-fragments (hoisted; launch_bounds(256,4) gives 128-VGPR budget)
    half8 qf[4];
    #pragma unroll
    for (int kd = 0; kd < 4; ++kd)
        qf[kd] = *(const half8*)&thetaT[((size_t)b * Nn + n0 + w * 16 + l16) * Cin
                                        + kd * 32 + quad * 8];

    floatx4 yacc[8] = {};
    float li[4] = {0.f, 0.f, 0.f, 0.f};

    for (int ch = 0; ch < 8; ++ch) {
        const int chg = kh * 8 + ch;          // global chunk id
        __syncthreads();                      // prev chunk's Ks reads done
        #pragma unroll
        for (int it = 0; it < 4; ++it) {
            int idx = t + 256 * it;
            int m = idx >> 4, d8 = idx & 15;
            *(uint4*)&Ks[m * DPAD + d8 * 8] =
                *(const uint4*)&phiPt[((size_t)b * Npl + chg * 64 + m) * Cin + d8 * 8];
        }
        __syncthreads();

        // S = Q K^T (fp16 MFMA)
        floatx4 sacc[4] = {};
        #pragma unroll
        for (int mt = 0; mt < 4; ++mt) {
            #pragma unroll
            for (int kd = 0; kd < 4; ++kd) {
                half8 kf = *(const half8*)&Ks[(mt * 16 + l16) * DPAD + kd * 32 + quad * 8];
                sacc[mt] = __builtin_amdgcn_mfma_f32_16x16x32_f16(qf[kd], kf, sacc[mt], 0, 0, 0);
            }
        }

        // P = exp(s - SSHIFT) bf16; per-lane denominator partials
        #pragma unroll
        for (int mt = 0; mt < 4; ++mt) {
            #pragma unroll
            for (int r = 0; r < 4; ++r) {
                float e = __expf(sacc[mt][r] - SSHIFT);
                li[r] += e;
                Ps[w][(quad * 4 + r) * PPAD + mt * 16 + l16] = f2bf(e);
            }
        }

        short8 pf[2];
        #pragma unroll
        for (int kd = 0; kd < 2; ++kd)
            pf[kd] = *(const short8*)&Ps[w][l16 * PPAD + kd * 32 + quad * 8];

        // Y += P V (bf16 MFMA), V^T fragments direct from global (L2-resident)
        #pragma unroll
        for (int ct = 0; ct < 8; ++ct) {
            #pragma unroll
            for (int kd = 0; kd < 2; ++kd) {
                short8 vf = *(const short8*)&gPc[((size_t)b * Cin + ct * 16 + l16) * Npl
                                                 + chg * 64 + kd * 32 + quad * 8];
                yacc[ct] = __builtin_amdgcn_mfma_f32_16x16x32_bf16(pf[kd], vf, yacc[ct], 0, 0, 0);
            }
        }
    }

    // write partials (no normalization)
    float* Yp = Ypart + ((size_t)(kh * Bn + b) * Nn) * Cin;
    float* Lp = Lpart + (size_t)(kh * Bn + b) * Nn;
    #pragma unroll
    for (int r = 0; r < 4; ++r) {
        #pragma unroll
        for (int o = 1; o < 16; o <<= 1) li[r] += __shfl_xor(li[r], o, 64);
        int q = n0 + w * 16 + quad * 4 + r;
        #pragma unroll
        for (int ct = 0; ct < 8; ++ct)
            Yp[(size_t)q * Cin + ct * 16 + l16] = yacc[ct][r];
        if (l16 == 0) Lp[q] = li[r];
    }
}

// ---------------------------------------------------------------------------
// Kernel 3: out = Wh @ y + cvec + x, with the split-K combine fused into
// staging: y = (Y0+Y1) / (L0+L1) -> fp16 LDS. fp16 MFMA.
// ---------------------------------------------------------------------------
__global__ __launch_bounds__(256) void k_out(
    const float* __restrict__ Ypart, const float* __restrict__ Lpart,
    const float* __restrict__ x,
    const unsigned short* __restrict__ Wh, const float* __restrict__ cvec,
    float* __restrict__ out)
{
    __shared__ __align__(16) unsigned short Ys[64 * DPAD];    // 17.4 KB
    __shared__ __align__(16) unsigned short Ws[128 * DPAD];   // 34.8 KB
    __shared__ float Linv[64];

    const int t    = threadIdx.x;
    const int w    = t >> 6;
    const int l    = t & 63;
    const int quad = l >> 4;
    const int l16  = l & 15;
    const int b    = blockIdx.x >> 6;
    const int qt   = blockIdx.x & 63;
    const int n0   = qt * 64;

    if (t < 64) {
        float l0 = Lpart[(size_t)b * Nn + n0 + t];
        float l1 = Lpart[(size_t)(Bn + b) * Nn + n0 + t];
        Linv[t] = 1.0f / (l0 + l1);
    }
    __syncthreads();

    // stage y tile: (Y0+Y1)*Linv -> fp16 [64 q x 128 c]
    {
        const float4* Y0 = (const float4*)(Ypart + ((size_t)b * Nn) * Cin);
        const float4* Y1 = (const float4*)(Ypart + ((size_t)(Bn + b) * Nn) * Cin);
        #pragma unroll
        for (int it = 0; it < 8; ++it) {
            int idx = t + 256 * it;              // 0..2047 float4
            int q  = idx >> 5;
            int c4 = idx & 31;
            size_t gi = ((size_t)(n0 + q) * Cin >> 2) + c4;
            float4 a = Y0[gi], c = Y1[gi];
            float s = Linv[q];
            ushort4 h;
            h.x = f2h((a.x + c.x) * s); h.y = f2h((a.y + c.y) * s);
            h.z = f2h((a.z + c.z) * s); h.w = f2h((a.w + c.w) * s);
            *(ushort4*)&Ys[q * DPAD + c4 * 4] = h;
        }
    }

    for (int oc = 0; oc < 2; ++oc) {
        __syncthreads();
        #pragma unroll
        for (int it = 0; it < 8; ++it) {
            int idx = t + 256 * it;
            int o = idx >> 4, d8 = idx & 15;
            *(uint4*)&Ws[o * DPAD + d8 * 8] =
                *(const uint4*)&Wh[((size_t)(oc * 128 + o)) * Cin + d8 * 8];
        }
        __syncthreads();

        half8 af[2][4];
        #pragma unroll
        for (int mt = 0; mt < 2; ++mt)
            #pragma unroll
            for (int kd = 0; kd < 4; ++kd)
                af[mt][kd] = *(const half8*)&Ws[(w * 32 + mt * 16 + l16) * DPAD + kd * 32 + quad * 8];

        floatx4 acc[2][4] = {};
        #pragma unroll
        for (int nt = 0; nt < 4; ++nt) {
            half8 bfr[4];
            #pragma unroll
            for (int kd = 0; kd < 4; ++kd)
                bfr[kd] = *(const half8*)&Ys[(nt * 16 + l16) * DPAD + kd * 32 + quad * 8];
            #pragma unroll
            for (int mt = 0; mt < 2; ++mt)
                #pragma unroll
                for (int kd = 0; kd < 4; ++kd)
                    acc[mt][nt] = __builtin_amdgcn_mfma_f32_16x16x32_f16(af[mt][kd], bfr[kd], acc[mt][nt], 0, 0, 0);
        }

        #pragma unroll
        for (int mt = 0; mt < 2; ++mt) {
            #pragma unroll
            for (int r = 0; r < 4; ++r) {
                int o = oc * 128 + w * 32 + mt * 16 + quad * 4 + r;
                float cv = cvec[o];
                #pragma unroll
                for (int nt = 0; nt < 4; ++nt) {
                    size_t gi = ((size_t)(b * Cc + o)) * Nn + n0 + nt * 16 + l16;
                    out[gi] = acc[mt][nt][r] + cv + x[gi];
                }
            }
        }
    }
}

// ---------------------------------------------------------------------------
extern "C" void kernel_launch(void* const* d_in, const int* in_sizes, int n_in,
                              void* d_out, int out_size, void* d_ws, size_t ws_size,
                              hipStream_t stream) {
    const float* x    = (const float*)d_in[0];
    const float* g_w  = (const float*)d_in[1];
    const float* g_b  = (const float*)d_in[2];
    const float* th_w = (const float*)d_in[3];
    const float* th_b = (const float*)d_in[4];
    const float* ph_w = (const float*)d_in[5];
    const float* ph_b = (const float*)d_in[6];
    const float* W_w  = (const float*)d_in[7];
    const float* W_b  = (const float*)d_in[8];
    const float* gmm  = (const float*)d_in[9];
    const float* bta  = (const float*)d_in[10];
    const float* mmn  = (const float*)d_in[11];
    const float* vvr  = (const float*)d_in[12];
    float* out = (float*)d_out;

    unsigned short* thetaT = (unsigned short*)d_ws;      // 8 MB fp16
    unsigned short* phiPt  = thetaT + (size_t)4194304;   // 2 MB fp16
    unsigned short* gPc    = phiPt + (size_t)1048576;    // 2 MB bf16
    unsigned short* Wh     = gPc + (size_t)1048576;      // 64 KB
    unsigned short* gWh    = Wh + 32768;
    unsigned short* thWh   = gWh + 32768;
    unsigned short* thWl   = thWh + 32768;
    unsigned short* phWh   = thWl + 32768;
    unsigned short* phWl   = phWh + 32768;
    float*          cvec   = (float*)(phWl + 32768);     // 1 KB
    float*          Ypart  = cvec + 256;                 // 2 x 16 MB fp32
    float*          Lpart  = Ypart + (size_t)2 * Bn * Nn * Cin;  // 256 KB

    k_prep<<<dim3(512), dim3(256), 0, stream>>>(
        g_w, th_w, ph_w, W_w, W_b, gmm, bta, mmn, vvr,
        gWh, thWh, thWl, phWh, phWl, Wh, cvec);
    k_conv3<<<dim3(Bn * 64), dim3(256), 0, stream>>>(
        x, gWh, thWh, thWl, phWh, phWl, g_b, th_b, ph_b, thetaT, gPc, phiPt);
    k_attn<<<dim3(Bn * 128), dim3(256), 0, stream>>>(thetaT, phiPt, gPc, Ypart, Lpart);
    k_out<<<dim3(Bn * 64), dim3(256), 0, stream>>>(Ypart, Lpart, x, Wh, cvec, out);
}

// Round 8
// 178.984 us; speedup vs baseline: 1.2471x; 1.2471x over previous
//
#include <hip/hip_runtime.h>
#include <math.h>

// Problem constants
#define Bn   8
#define Cc   256     // input channels
#define Cin  128     // inter channels
#define Hh   64
#define Ww   64
#define Nn   4096    // H*W
#define Npl  1024    // pooled pixels (32*32)
#define EPSf 1e-5f

typedef __attribute__((ext_vector_type(8))) short    short8;   // 8 bf16
typedef __attribute__((ext_vector_type(8))) _Float16 half8;    // 8 fp16
typedef __attribute__((ext_vector_type(4))) float    floatx4;  // MFMA C/D

__device__ __forceinline__ unsigned short f2bf(float f) {
    unsigned int u = __float_as_uint(f);
    u += 0x7fffu + ((u >> 16) & 1u);
    return (unsigned short)(u >> 16);
}
__device__ __forceinline__ unsigned short f2h(float f) {
    _Float16 h = (_Float16)f;
    return __builtin_bit_cast(unsigned short, h);
}
__device__ __forceinline__ float h2f(unsigned short u) {
    return (float)__builtin_bit_cast(_Float16, u);
}

// ---------------------------------------------------------------------------
// Kernel 0 (prep): fp16 weight variants.
//  - g: fp16 hi. theta/phi: fp16 hi + fp16 lo (hi+lo ~ 22-bit mantissa).
//  - Wh = fp16(W_w * gamma/sqrt(var+eps)); cvec = (W_b-mean)*inv + beta.
// ---------------------------------------------------------------------------
__global__ __launch_bounds__(256) void k_prep(
    const float* __restrict__ g_w, const float* __restrict__ th_w,
    const float* __restrict__ ph_w,
    const float* __restrict__ W_w, const float* __restrict__ W_b,
    const float* __restrict__ gamma, const float* __restrict__ beta,
    const float* __restrict__ mean,  const float* __restrict__ var,
    unsigned short* __restrict__ gWh,
    unsigned short* __restrict__ thWh, unsigned short* __restrict__ thWl,
    unsigned short* __restrict__ phWh, unsigned short* __restrict__ phWl,
    unsigned short* __restrict__ Wh, float* __restrict__ cvec)
{
    int i = blockIdx.x * 256 + threadIdx.x;
    if (i < 98304) {                          // 3 x 128 x 256 conv weights
        int seg = i >> 15;                    // 0:g 1:theta 2:phi
        int idx = i & 32767;
        float v = (seg == 0 ? g_w : (seg == 1 ? th_w : ph_w))[idx];
        unsigned short hi = f2h(v);
        if (seg == 0) gWh[idx] = hi;
        else {
            (seg == 1 ? thWh : phWh)[idx] = hi;
            (seg == 1 ? thWl : phWl)[idx] = f2h(v - h2f(hi));
        }
    } else {
        int j = i - 98304;                    // 0..32767 : W fold (256x128)
        int o = j >> 7;
        float inv = gamma[o] * rsqrtf(var[o] + EPSf);
        Wh[j] = f2h(W_w[j] * inv);
        if (j < Cc) {
            float invi = gamma[j] * rsqrtf(var[j] + EPSf);
            cvec[j] = (W_b[j] - mean[j]) * invi + beta[j];
        }
    }
}

// ---------------------------------------------------------------------------
// Kernel 1: fused conv1x1 g/theta/phi via fp16 MFMA, split-precision on
// theta/phi (hi*hi + hi*lo + lo*hi). Outputs:
//   thetaT: [B,4096,128] fp16   phiPt: [B,1024,128] fp16   gPc: [B,128,1024] bf16
// ---------------------------------------------------------------------------
#define XPAD 264

__global__ __launch_bounds__(256, 2) void k_conv3(
    const float* __restrict__ x,
    const unsigned short* __restrict__ gWh,
    const unsigned short* __restrict__ thWh, const unsigned short* __restrict__ thWl,
    const unsigned short* __restrict__ phWh, const unsigned short* __restrict__ phWl,
    const float* __restrict__ g_b, const float* __restrict__ th_b,
    const float* __restrict__ ph_b,
    unsigned short* __restrict__ thetaT,
    unsigned short* __restrict__ gPc,
    unsigned short* __restrict__ phiPt)
{
    __shared__ __align__(16) unsigned short Xhi[64 * XPAD];   // 33 KB
    __shared__ __align__(16) unsigned short Xlo[64 * XPAD];   // 33 KB

    const int t    = threadIdx.x;
    const int w    = t >> 6;
    const int l    = t & 63;
    const int quad = l >> 4;
    const int l16  = l & 15;
    const int b    = blockIdx.x >> 6;
    const int tile = blockIdx.x & 63;
    const int ty   = tile >> 1;
    const int tx   = tile & 1;

    {
        const float4* xg = (const float4*)x;
        unsigned int* XhiW = (unsigned int*)Xhi;
        unsigned int* XloW = (unsigned int*)Xlo;
        #pragma unroll
        for (int it = 0; it < 8; ++it) {
            int idx = t + 256 * it;          // 0..2047
            int c2  = idx >> 4;
            int p4  = idx & 15;
            int n   = (2 * ty + (p4 >> 3)) * Ww + tx * 32 + (p4 & 7) * 4;
            float4 va = xg[((size_t)(b * Cc + 2 * c2) * Nn + n) >> 2];
            float4 vb = xg[((size_t)(b * Cc + 2 * c2 + 1) * Nn + n) >> 2];
            const float fa[4] = {va.x, va.y, va.z, va.w};
            const float fb[4] = {vb.x, vb.y, vb.z, vb.w};
            #pragma unroll
            for (int i = 0; i < 4; ++i) {
                int px = p4 * 4 + i;
                unsigned short ha = f2h(fa[i]), hb = f2h(fb[i]);
                unsigned short la = f2h(fa[i] - h2f(ha));
                unsigned short lb = f2h(fb[i] - h2f(hb));
                XhiW[px * 132 + c2] = (unsigned int)ha | ((unsigned int)hb << 16);
                XloW[px * 132 + c2] = (unsigned int)la | ((unsigned int)lb << 16);
            }
        }
    }
    __syncthreads();

    floatx4 acc[6][4] = {};

    #pragma unroll 2
    for (int kd = 0; kd < 8; ++kd) {
        half8 bhi[4], blo[4];
        #pragma unroll
        for (int nt = 0; nt < 4; ++nt) {
            bhi[nt] = *(const half8*)&Xhi[(nt * 16 + l16) * XPAD + kd * 32 + quad * 8];
            blo[nt] = *(const half8*)&Xlo[(nt * 16 + l16) * XPAD + kd * 32 + quad * 8];
        }
        #pragma unroll
        for (int ti = 0; ti < 6; ++ti) {
            int ot  = w + 4 * ti;
            int seg = ot >> 3;
            size_t aoff = (size_t)((ot & 7) * 16 + l16) * Cc + kd * 32 + quad * 8;
            const unsigned short* wh = (seg == 0 ? gWh : (seg == 1 ? thWh : phWh));
            half8 ah = *(const half8*)&wh[aoff];
            #pragma unroll
            for (int nt = 0; nt < 4; ++nt)
                acc[ti][nt] = __builtin_amdgcn_mfma_f32_16x16x32_f16(ah, bhi[nt], acc[ti][nt], 0, 0, 0);
            if (seg != 0) {
                const unsigned short* wl = (seg == 1 ? thWl : phWl);
                half8 al = *(const half8*)&wl[aoff];
                #pragma unroll
                for (int nt = 0; nt < 4; ++nt) {
                    acc[ti][nt] = __builtin_amdgcn_mfma_f32_16x16x32_f16(ah, blo[nt], acc[ti][nt], 0, 0, 0);
                    acc[ti][nt] = __builtin_amdgcn_mfma_f32_16x16x32_f16(al, bhi[nt], acc[ti][nt], 0, 0, 0);
                }
            }
        }
    }

    // epilogue: D[row=quad*4+r][col=l16]
    #pragma unroll
    for (int ti = 0; ti < 6; ++ti) {
        int ot  = w + 4 * ti;
        int seg = ot >> 3;
        int ol  = (ot & 7) * 16 + quad * 4;
        if (seg == 1) {                            // theta -> fp16 [n][o]
            float b0 = th_b[ol], b1 = th_b[ol + 1], b2 = th_b[ol + 2], b3 = th_b[ol + 3];
            #pragma unroll
            for (int nt = 0; nt < 4; ++nt) {
                int n = (2 * ty + (nt >> 1)) * Ww + tx * 32 + (nt & 1) * 16 + l16;
                ushort4 v;
                v.x = f2h(acc[ti][nt][0] + b0);
                v.y = f2h(acc[ti][nt][1] + b1);
                v.z = f2h(acc[ti][nt][2] + b2);
                v.w = f2h(acc[ti][nt][3] + b3);
                *(ushort4*)&thetaT[((size_t)b * Nn + n) * Cin + ol] = v;
            }
        } else {                                   // g / phi: 2x2 maxpool
            const float* bb = (seg == 0 ? g_b : ph_b);
            float b0 = bb[ol], b1 = bb[ol + 1], b2 = bb[ol + 2], b3 = bb[ol + 3];
            #pragma unroll
            for (int pp = 0; pp < 2; ++pp) {
                float pm[4];
                #pragma unroll
                for (int r = 0; r < 4; ++r) {
                    float m = fmaxf(acc[ti][pp][r], acc[ti][pp + 2][r]);
                    pm[r] = fmaxf(m, __shfl_xor(m, 1, 64));
                }
                int np = ty * 32 + tx * 16 + pp * 8 + (l16 >> 1);
                if ((l16 & 1) == 0) {
                    if (seg == 0) {                // g -> bf16 [o][np] (V dtype)
                        gPc[((size_t)b * Cin + ol + 0) * Npl + np] = f2bf(pm[0] + b0);
                        gPc[((size_t)b * Cin + ol + 1) * Npl + np] = f2bf(pm[1] + b1);
                        gPc[((size_t)b * Cin + ol + 2) * Npl + np] = f2bf(pm[2] + b2);
                        gPc[((size_t)b * Cin + ol + 3) * Npl + np] = f2bf(pm[3] + b3);
                    } else {                       // phi -> fp16 [np][o]
                        ushort4 v;
                        v.x = f2h(pm[0] + b0); v.y = f2h(pm[1] + b1);
                        v.z = f2h(pm[2] + b2); v.w = f2h(pm[3] + b3);
                        *(ushort4*)&phiPt[((size_t)b * Npl + np) * Cin + ol] = v;
                    }
                }
            }
        }
    }
}

// ---------------------------------------------------------------------------
// Kernel 2: flash attention, split-K=2 (512 keys each), fp16 QK^T MFMA,
// bf16 PV MFMA, fixed-shift softmax. K and V^T both STAGED IN LDS (R5
// structure — fragment loads from global inside the K-loop were the R6/R7
// regression). Per-half normalized fp16 partials:
//   Yh fp16 [2][B,N,128] = Y_half / l_half,  Lpart fp32 [2][B,N] = l_half
// LDS 44.5 KB -> 3 blocks/CU. Q frags from global, pinned vs remat by asm.
// ---------------------------------------------------------------------------
#define DPAD 136
#define VPAD 72
#define PPAD 68
#define SSHIFT 20.0f

__global__ __launch_bounds__(256, 3) void k_attn(
    const unsigned short* __restrict__ thetaT,
    const unsigned short* __restrict__ phiPt,
    const unsigned short* __restrict__ gPc,
    unsigned short* __restrict__ Yh, float* __restrict__ Lpart)
{
    __shared__ __align__(16) unsigned short Ks[64 * DPAD];     // 17.4 KB
    __shared__ __align__(16) unsigned short Vt[Cin * VPAD];    // 18.4 KB
    __shared__ __align__(16) unsigned short Ps[4][16 * PPAD];  // 8.7 KB

    const int t    = threadIdx.x;
    const int w    = t >> 6;
    const int l    = t & 63;
    const int quad = l >> 4;
    const int l16  = l & 15;
    const int b    = blockIdx.x >> 7;
    const int kh   = (blockIdx.x >> 6) & 1;   // K half
    const int qb   = blockIdx.x & 63;
    const int n0   = qb * 64;

    // Q A-fragments, loaded ONCE; empty asm pins them in VGPRs (no remat)
    uint4 qr[4];
    #pragma unroll
    for (int kd = 0; kd < 4; ++kd)
        qr[kd] = *(const uint4*)&thetaT[((size_t)b * Nn + n0 + w * 16 + l16) * Cin
                                        + kd * 32 + quad * 8];
    #pragma unroll
    for (int kd = 0; kd < 4; ++kd)
        asm volatile("" : "+v"(qr[kd].x), "+v"(qr[kd].y), "+v"(qr[kd].z), "+v"(qr[kd].w));
    half8 qf[4];
    #pragma unroll
    for (int kd = 0; kd < 4; ++kd) qf[kd] = __builtin_bit_cast(half8, qr[kd]);

    floatx4 yacc[8] = {};
    float li[4] = {0.f, 0.f, 0.f, 0.f};

    for (int ch = 0; ch < 8; ++ch) {
        const int chg = kh * 8 + ch;          // global chunk id
        __syncthreads();                      // prev chunk's LDS reads done
        // stage K chunk [64 m x 128 d] fp16
        #pragma unroll
        for (int it = 0; it < 4; ++it) {
            int idx = t + 256 * it;
            int m = idx >> 4, d8 = idx & 15;
            *(uint4*)&Ks[m * DPAD + d8 * 8] =
                *(const uint4*)&phiPt[((size_t)b * Npl + chg * 64 + m) * Cin + d8 * 8];
        }
        // stage V^T chunk Vt[c][m] (128 c x 64 m) bf16 from channel-major gPc
        #pragma unroll
        for (int it = 0; it < 4; ++it) {
            int idx = t + 256 * it;
            int c = idx >> 3, m8 = idx & 7;
            *(uint4*)&Vt[c * VPAD + m8 * 8] =
                *(const uint4*)&gPc[((size_t)b * Cin + c) * Npl + chg * 64 + m8 * 8];
        }
        __syncthreads();

        // S = Q K^T (fp16 MFMA): 4 m-tiles x 4 k-depth
        floatx4 sacc[4] = {};
        #pragma unroll
        for (int mt = 0; mt < 4; ++mt) {
            #pragma unroll
            for (int kd = 0; kd < 4; ++kd) {
                half8 kf = *(const half8*)&Ks[(mt * 16 + l16) * DPAD + kd * 32 + quad * 8];
                sacc[mt] = __builtin_amdgcn_mfma_f32_16x16x32_f16(qf[kd], kf, sacc[mt], 0, 0, 0);
            }
        }

        // P = exp(s - SSHIFT) bf16; per-lane denominator partials
        #pragma unroll
        for (int mt = 0; mt < 4; ++mt) {
            #pragma unroll
            for (int r = 0; r < 4; ++r) {
                float e = __expf(sacc[mt][r] - SSHIFT);
                li[r] += e;
                Ps[w][(quad * 4 + r) * PPAD + mt * 16 + l16] = f2bf(e);
            }
        }

        short8 pf[2];
        #pragma unroll
        for (int kd = 0; kd < 2; ++kd)
            pf[kd] = *(const short8*)&Ps[w][l16 * PPAD + kd * 32 + quad * 8];

        // Y += P V (bf16 MFMA): 8 c-tiles x 2 k-depth, V frags from LDS
        #pragma unroll
        for (int ct = 0; ct < 8; ++ct) {
            #pragma unroll
            for (int kd = 0; kd < 2; ++kd) {
                short8 vf = *(const short8*)&Vt[(ct * 16 + l16) * VPAD + kd * 32 + quad * 8];
                yacc[ct] = __builtin_amdgcn_mfma_f32_16x16x32_bf16(pf[kd], vf, yacc[ct], 0, 0, 0);
            }
        }
    }

    // per-half normalize; store fp16 partial + denominator
    unsigned short* Yp = Yh + ((size_t)(kh * Bn + b) * Nn) * Cin;
    float* Lp = Lpart + (size_t)(kh * Bn + b) * Nn;
    #pragma unroll
    for (int r = 0; r < 4; ++r) {
        #pragma unroll
        for (int o = 1; o < 16; o <<= 1) li[r] += __shfl_xor(li[r], o, 64);
        float il = 1.0f / li[r];
        int q = n0 + w * 16 + quad * 4 + r;
        #pragma unroll
        for (int ct = 0; ct < 8; ++ct)
            Yp[(size_t)q * Cin + ct * 16 + l16] = f2h(yacc[ct][r] * il);
        if (l16 == 0) Lp[q] = li[r];
    }
}

// ---------------------------------------------------------------------------
// Kernel 3: out = Wh @ y + cvec + x, split-K combine fused into staging:
//   y = (l0*y0 + l1*y1)/(l0+l1) -> fp16 LDS. fp16 MFMA.
// ---------------------------------------------------------------------------
__global__ __launch_bounds__(256) void k_out(
    const unsigned short* __restrict__ Yh, const float* __restrict__ Lpart,
    const float* __restrict__ x,
    const unsigned short* __restrict__ Wh, const float* __restrict__ cvec,
    float* __restrict__ out)
{
    __shared__ __align__(16) unsigned short Ys[64 * DPAD];    // 17.4 KB
    __shared__ __align__(16) unsigned short Ws[128 * DPAD];   // 34.8 KB
    __shared__ float w0s[64], w1s[64];

    const int t    = threadIdx.x;
    const int w    = t >> 6;
    const int l    = t & 63;
    const int quad = l >> 4;
    const int l16  = l & 15;
    const int b    = blockIdx.x >> 6;
    const int qt   = blockIdx.x & 63;
    const int n0   = qt * 64;

    if (t < 64) {
        float l0 = Lpart[(size_t)b * Nn + n0 + t];
        float l1 = Lpart[(size_t)(Bn + b) * Nn + n0 + t];
        float s  = 1.0f / (l0 + l1);
        w0s[t] = l0 * s;
        w1s[t] = l1 * s;
    }
    __syncthreads();

    // stage y tile: weighted combine of fp16 halves -> fp16 [64 q x 128 c]
    {
        const uint4* Y0 = (const uint4*)(Yh + ((size_t)b * Nn) * Cin);
        const uint4* Y1 = (const uint4*)(Yh + ((size_t)(Bn + b) * Nn) * Cin);
        #pragma unroll
        for (int it = 0; it < 4; ++it) {
            int idx = t + 256 * it;              // 0..1023 (8 fp16 units)
            int q  = idx >> 4;
            int d8 = idx & 15;
            size_t gi = (((size_t)(n0 + q) * Cin) >> 3) + d8;
            half8 a = __builtin_bit_cast(half8, Y0[gi]);
            half8 c = __builtin_bit_cast(half8, Y1[gi]);
            float w0 = w0s[q], w1 = w1s[q];
            half8 r;
            #pragma unroll
            for (int i = 0; i < 8; ++i)
                r[i] = (_Float16)(w0 * (float)a[i] + w1 * (float)c[i]);
            *(uint4*)&Ys[q * DPAD + d8 * 8] = __builtin_bit_cast(uint4, r);
        }
    }

    for (int oc = 0; oc < 2; ++oc) {
        __syncthreads();
        #pragma unroll
        for (int it = 0; it < 8; ++it) {
            int idx = t + 256 * it;
            int o = idx >> 4, d8 = idx & 15;
            *(uint4*)&Ws[o * DPAD + d8 * 8] =
                *(const uint4*)&Wh[((size_t)(oc * 128 + o)) * Cin + d8 * 8];
        }
        __syncthreads();

        half8 af[2][4];
        #pragma unroll
        for (int mt = 0; mt < 2; ++mt)
            #pragma unroll
            for (int kd = 0; kd < 4; ++kd)
                af[mt][kd] = *(const half8*)&Ws[(w * 32 + mt * 16 + l16) * DPAD + kd * 32 + quad * 8];

        floatx4 acc[2][4] = {};
        #pragma unroll
        for (int nt = 0; nt < 4; ++nt) {
            half8 bfr[4];
            #pragma unroll
            for (int kd = 0; kd < 4; ++kd)
                bfr[kd] = *(const half8*)&Ys[(nt * 16 + l16) * DPAD + kd * 32 + quad * 8];
            #pragma unroll
            for (int mt = 0; mt < 2; ++mt)
                #pragma unroll
                for (int kd = 0; kd < 4; ++kd)
                    acc[mt][nt] = __builtin_amdgcn_mfma_f32_16x16x32_f16(af[mt][kd], bfr[kd], acc[mt][nt], 0, 0, 0);
        }

        #pragma unroll
        for (int mt = 0; mt < 2; ++mt) {
            #pragma unroll
            for (int r = 0; r < 4; ++r) {
                int o = oc * 128 + w * 32 + mt * 16 + quad * 4 + r;
                float cv = cvec[o];
                #pragma unroll
                for (int nt = 0; nt < 4; ++nt) {
                    size_t gi = ((size_t)(b * Cc + o)) * Nn + n0 + nt * 16 + l16;
                    out[gi] = acc[mt][nt][r] + cv + x[gi];
                }
            }
        }
    }
}

// ---------------------------------------------------------------------------
extern "C" void kernel_launch(void* const* d_in, const int* in_sizes, int n_in,
                              void* d_out, int out_size, void* d_ws, size_t ws_size,
                              hipStream_t stream) {
    const float* x    = (const float*)d_in[0];
    const float* g_w  = (const float*)d_in[1];
    const float* g_b  = (const float*)d_in[2];
    const float* th_w = (const float*)d_in[3];
    const float* th_b = (const float*)d_in[4];
    const float* ph_w = (const float*)d_in[5];
    const float* ph_b = (const float*)d_in[6];
    const float* W_w  = (const float*)d_in[7];
    const float* W_b  = (const float*)d_in[8];
    const float* gmm  = (const float*)d_in[9];
    const float* bta  = (const float*)d_in[10];
    const float* mmn  = (const float*)d_in[11];
    const float* vvr  = (const float*)d_in[12];
    float* out = (float*)d_out;

    unsigned short* thetaT = (unsigned short*)d_ws;      // 8 MB fp16
    unsigned short* phiPt  = thetaT + (size_t)4194304;   // 2 MB fp16
    unsigned short* gPc    = phiPt + (size_t)1048576;    // 2 MB bf16
    unsigned short* Wh     = gPc + (size_t)1048576;      // 64 KB
    unsigned short* gWh    = Wh + 32768;
    unsigned short* thWh   = gWh + 32768;
    unsigned short* thWl   = thWh + 32768;
    unsigned short* phWh   = thWl + 32768;
    unsigned short* phWl   = phWh + 32768;
    float*          cvec   = (float*)(phWl + 32768);     // 1 KB
    unsigned short* Yh     = (unsigned short*)(cvec + 256);  // 2 x 8 MB fp16
    float*          Lpart  = (float*)(Yh + (size_t)2 * Bn * Nn * Cin);  // 256 KB

    k_prep<<<dim3(512), dim3(256), 0, stream>>>(
        g_w, th_w, ph_w, W_w, W_b, gmm, bta, mmn, vvr,
        gWh, thWh, thWl, phWh, phWl, Wh, cvec);
    k_conv3<<<dim3(Bn * 64), dim3(256), 0, stream>>>(
        x, gWh, thWh, thWl, phWh, phWl, g_b, th_b, ph_b, thetaT, gPc, phiPt);
    k_attn<<<dim3(Bn * 128), dim3(256), 0, stream>>>(thetaT, phiPt, gPc, Yh, Lpart);
    k_out<<<dim3(Bn * 64), dim3(256), 0, stream>>>(Yh, Lpart, x, Wh, cvec, out);
}